// Round 20
// baseline (280.064 us; speedup 1.0000x reference)
//
#include <hip/hip_runtime.h>

// Problem constants
#define B_Q   4096
#define E_DIM 512
#define N_C   2000
#define N_P   64000

// Round 19: r18's barrier-free LDS-free design, SPILL-FREE.  r18 spilled
// (WRITE 68MB = 32 out + 36 scratch; A[4][8] 128 + acc 64 + B 32 + temps >
// the 256-VGPR cap imposed by __launch_bounds__(256,2)) -> A re-read from
// scratch 8x inside the cc loop, MfmaUtil 29%.  Fix: ONE-WAVE BLOCKS (64
// threads, __launch_bounds__(64,1)) lift the cap to 512 VGPR; demand ~250
// fits with zero spill and still allows 2 waves/SIMD.  Everything else is
// r18 verbatim: both operands fragment-packed by normq (r17-verified
// transform), wave owns 64 rows x 512 cols, A register-resident, B streamed
// as 4x1KB coalesced L2 loads per k-tile with dual-set prefetch.  Zero
// s_barrier, zero LDS, zero lgkm in the k-loop.
// Sentinels: WRITE_SIZE ~32MB & FETCH ~25-30MB = spill gone.

typedef int i32x4 __attribute__((ext_vector_type(4)));

// ---------------------------------------------------------------------------
// Row L2-normalize + per-row-scaled int8 quantization + FRAGMENT PACKING
// (both inputs).  For row c = c16*16 + r, element k = kt*64 + kg*16 + b:
//   dst[(c16*8 + kt)*1024 + (kg*16 + r)*16 + b]
// A wave's fragment load for (c16, kt) is dst[(c16*8+kt)*1024 + lane*16]
// -- one contiguous 1KB transaction.  (Transform verified on HW in r17.)
// ---------------------------------------------------------------------------
__global__ __launch_bounds__(128) void normq_kernel(
    const float* __restrict__ w1, const float* __restrict__ data,
    signed char* __restrict__ wqf, signed char* __restrict__ dqf,
    float* __restrict__ wsc, float* __restrict__ dsc)
{
  int row = blockIdx.x;
  const bool isW = (row < N_P);
  const float* in;
  signed char* dst; float* sc;
  if (isW) { in = w1;   dst = wqf; sc = wsc; }
  else     { in = data; dst = dqf; sc = dsc; row -= N_P; }
  const int tid = threadIdx.x;
  const float4 v = *(const float4*)(in + (size_t)row * E_DIM + tid * 4);
  float ss = v.x*v.x + v.y*v.y + v.z*v.z + v.w*v.w;
  float am = fmaxf(fmaxf(fabsf(v.x), fabsf(v.y)), fmaxf(fabsf(v.z), fabsf(v.w)));
  #pragma unroll
  for (int s = 1; s < 64; s <<= 1) {
    ss += __shfl_xor(ss, s);
    am = fmaxf(am, __shfl_xor(am, s));
  }
  __shared__ float pss[2], pam[2];
  if ((tid & 63) == 0) { pss[tid >> 6] = ss; pam[tid >> 6] = am; }
  __syncthreads();
  const float inv = 1.0f / fmaxf(sqrtf(pss[0] + pss[1]), 1e-12f);
  const float m   = fmaxf(fmaxf(pam[0], pam[1]) * inv, 1e-20f);
  const float qs  = 127.0f / m * inv;          // v * qs in [-127, 127]
  char4 o;
  o.x = (signed char)__float2int_rn(v.x * qs);
  o.y = (signed char)__float2int_rn(v.y * qs);
  o.z = (signed char)__float2int_rn(v.z * qs);
  o.w = (signed char)__float2int_rn(v.w * qs);
  // k = tid*4: kt = tid>>4, kg = (tid>>2)&3, byte-in-chunk = (tid&3)*4
  const int c16 = row >> 4, r = row & 15;
  const int kt = tid >> 4, kg = (tid >> 2) & 3;
  *(char4*)(dst + (size_t)(c16 * 8 + kt) * 1024 + (kg * 16 + r) * 16
                + (tid & 3) * 4) = o;
  if (tid == 0) sc[row] = m * (1.0f / 127.0f);
}

// ---------------------------------------------------------------------------
// Per-wave GEMM+max: wave (= block) covers rows [rowGroup*64, +64) x cols
// [colOct*512, +512).  A[4 m-tiles][8 kt] register-resident (128 VGPR).
// Sweep 8 col-groups (64 cols = 4 c16-tiles); per kt: 4 B loads (1KB
// coalesced each) + 16 MFMA; B dual-set, kt7 prefetches next col-group's
// kt0 (always issued; harmless over-read inside d_ws for the last group).
// No barriers, no LDS; load->MFMA ordering via compiler auto-waitcnt.
// ---------------------------------------------------------------------------
#define MF(a,b,c) __builtin_amdgcn_mfma_i32_16x16x64_i8(a, b, c, 0, 0, 0)

#define LDB(S,OFF,KT) do { \
  b##S##0 = *(const i32x4*)(gBc + (OFF) + (0*8+(KT))*1024); \
  b##S##1 = *(const i32x4*)(gBc + (OFF) + (1*8+(KT))*1024); \
  b##S##2 = *(const i32x4*)(gBc + (OFF) + (2*8+(KT))*1024); \
  b##S##3 = *(const i32x4*)(gBc + (OFF) + (3*8+(KT))*1024); \
} while(0)

#define MFMA_KT(S,KT) do { \
  acc[0][0]=MF(A[0][KT],b##S##0,acc[0][0]); acc[0][1]=MF(A[0][KT],b##S##1,acc[0][1]); \
  acc[0][2]=MF(A[0][KT],b##S##2,acc[0][2]); acc[0][3]=MF(A[0][KT],b##S##3,acc[0][3]); \
  acc[1][0]=MF(A[1][KT],b##S##0,acc[1][0]); acc[1][1]=MF(A[1][KT],b##S##1,acc[1][1]); \
  acc[1][2]=MF(A[1][KT],b##S##2,acc[1][2]); acc[1][3]=MF(A[1][KT],b##S##3,acc[1][3]); \
  acc[2][0]=MF(A[2][KT],b##S##0,acc[2][0]); acc[2][1]=MF(A[2][KT],b##S##1,acc[2][1]); \
  acc[2][2]=MF(A[2][KT],b##S##2,acc[2][2]); acc[2][3]=MF(A[2][KT],b##S##3,acc[2][3]); \
  acc[3][0]=MF(A[3][KT],b##S##0,acc[3][0]); acc[3][1]=MF(A[3][KT],b##S##1,acc[3][1]); \
  acc[3][2]=MF(A[3][KT],b##S##2,acc[3][2]); acc[3][3]=MF(A[3][KT],b##S##3,acc[3][3]); \
} while(0)

__global__ __launch_bounds__(64, 1) void gemm_max_kernel(
    const signed char* __restrict__ wqf,  // [4000][8][1024] fragment-packed
    const signed char* __restrict__ dqf,  // [256][8][1024]  fragment-packed
    const float* __restrict__ wsc,        // [64000] dequant scales
    const float* __restrict__ dsc,        // [4096]  dequant scales
    float* __restrict__ out)              // [2000][4096]
{
  const int lane = threadIdx.x & 63;

  // XCD-aware bijective swizzle: 8000 one-wave blocks, 1000/XCD.
  const int bid  = blockIdx.x;
  const int w    = (bid & 7) * 1000 + (bid >> 3);   // wave id 0..7999
  const int rowGroup = w >> 3;            // 0..999   (64 rows each)
  const int colOct   = w & 7;             // 0..7     (512 cols each)

  // A: all 32 fragments register-resident.  r16-tile = rowGroup*4 + m.
  const signed char* gAp = wqf + (size_t)rowGroup * 32768 + lane * 16;
  i32x4 A[4][8];
  #pragma unroll
  for (int m = 0; m < 4; ++m)
    #pragma unroll
    for (int kt = 0; kt < 8; ++kt)
      A[m][kt] = *(const i32x4*)(gAp + (m * 8 + kt) * 1024);

  // B base for first col-group; advances by 32768 per group.
  const signed char* gBc = dqf + (size_t)colOct * 8 * 32768 + lane * 16;

  const int r  = lane & 15;
  const int kg = lane >> 4;

  i32x4 b00, b01, b02, b03, b10, b11, b12, b13;
  i32x4 acc[4][4];

  // Prologue: B(kt0) of first col-group into set 0.
  LDB(0, 0, 0);

  float* outp = out + (size_t)(rowGroup * 2) * B_Q + colOct * 512;
  const float* wscp = wsc + rowGroup * 64 + kg * 4;
  const float* dscp = dsc + colOct * 512 + r;

  #pragma unroll 1
  for (int cc = 0; cc < 8; ++cc) {
    #pragma unroll
    for (int m = 0; m < 4; ++m)
      #pragma unroll
      for (int n = 0; n < 4; ++n)
        acc[m][n] = (i32x4){0, 0, 0, 0};

    // kt loop, fully unrolled; set(kt) = kt&1; during kt load set(kt+1).
    LDB(1, 0, 1);       MFMA_KT(0, 0);
    LDB(0, 0, 2);       MFMA_KT(1, 1);
    LDB(1, 0, 3);       MFMA_KT(0, 2);
    LDB(0, 0, 4);       MFMA_KT(1, 3);
    LDB(1, 0, 5);       MFMA_KT(0, 4);
    LDB(0, 0, 6);       MFMA_KT(1, 5);
    LDB(1, 0, 7);       MFMA_KT(0, 6);
    LDB(0, 32768, 0);   MFMA_KT(1, 7);   // prefetch next col-group's kt0

    // Epilogue for this 64-col group: dequant + per-class max.
    // Wave row = m*16 + kg*4 + j; class q = m>>1.  Row scale BEFORE max.
    #pragma unroll
    for (int q = 0; q < 2; ++q) {
      const float4 w0 = *(const float4*)(wscp + (2*q)     * 16);
      const float4 w1 = *(const float4*)(wscp + (2*q + 1) * 16);
      #pragma unroll
      for (int n = 0; n < 4; ++n) {
        float pm = fmaxf(fmaxf((float)acc[2*q][n][0]   * w0.x,
                               (float)acc[2*q][n][1]   * w0.y),
                         fmaxf((float)acc[2*q][n][2]   * w0.z,
                               (float)acc[2*q][n][3]   * w0.w));
        pm = fmaxf(pm, fmaxf(fmaxf((float)acc[2*q+1][n][0] * w1.x,
                                   (float)acc[2*q+1][n][1] * w1.y),
                             fmaxf((float)acc[2*q+1][n][2] * w1.z,
                                   (float)acc[2*q+1][n][3] * w1.w)));
        pm = fmaxf(pm, __shfl_xor(pm, 16));
        pm = fmaxf(pm, __shfl_xor(pm, 32));
        if (lane < 16)
          outp[(size_t)q * B_Q + cc * 64 + n * 16 + r]
              = pm * dscp[cc * 64 + n * 16];
      }
    }
    gBc += 32768;
  }
}

// ---------------------------------------------------------------------------
extern "C" void kernel_launch(void* const* d_in, const int* in_sizes, int n_in,
                              void* d_out, int out_size, void* d_ws, size_t ws_size,
                              hipStream_t stream) {
  const float* data = (const float*)d_in[0];   // [4096][512]
  const float* w1   = (const float*)d_in[1];   // [64000][512]
  float* out = (float*)d_out;                  // [2000][4096]

  signed char* wqf = (signed char*)d_ws;                      // 32.77 MB
  signed char* dqf = wqf + (size_t)N_P * E_DIM;               //  2.10 MB
  float* wsc = (float*)(dqf + (size_t)B_Q * E_DIM);           // 256 KB
  float* dsc = wsc + N_P;                                     //  16 KB

  normq_kernel<<<N_P + B_Q, 128, 0, stream>>>(w1, data, wqf, dqf, wsc, dsc);
  gemm_max_kernel<<<8000, 64, 0, stream>>>(wqf, dqf, wsc, dsc, out);
}

// Round 21
// 190.879 us; speedup vs baseline: 1.4672x; 1.4672x over previous
//
#include <hip/hip_runtime.h>

// Problem constants
#define B_Q   4096
#define E_DIM 512
#define N_C   2000
#define N_P   64000

// Round 20: barrier-free LDS-free int8 GEMM with 32x32x32 MFMA.
// r18 (256-cap forced) spilled at demand ~280; r19 (uncapped) used >256 ->
// 1 wave/SIMD, latency-exposed.  32x32x32_i8 cuts register demand to ~230
// (B frags/kstep: 2x4 regs vs 4x4) so launch_bounds(256,2) force-fits ->
// 2 waves/SIMD spill-free -- AND halves MFMA instruction count at +12% rate
// (4404 vs 3944 TOPS).  Wave owns 64 rows x 512 cols: A (2 tiles x 16 ks)
// register-resident, B streamed as 1KB-coalesced L2 loads, dual-set
// prefetched 2 ksteps ahead (292cyc MFMA cover > L2 latency).  Zero
// s_barrier / LDS / lgkm in the k-loop; compiler emits exact counted vmcnt.
// 32x32 C/D layout HW-verified this session (r6 passed absmax); A/B packing
// mirrors the r12-verified 16x16 pattern via the r17-verified transform.

typedef int i32x4  __attribute__((ext_vector_type(4)));
typedef int i32x16 __attribute__((ext_vector_type(16)));

// ---------------------------------------------------------------------------
// Row L2-normalize + per-row-scaled int8 quantization + 32-TILE FRAGMENT
// PACKING (both inputs).  For row c = c32*32 + rr, element k = ks*32 + hi*16
// + b (b<16):  dst[(c32*16 + ks)*1024 + (hi*32 + rr)*16 + b].
// A wave's fragment load for (c32, ks) is dst[(c32*16+ks)*1024 + lane*16]:
// lane l -> row l&31, k = ks*32 + (l>>5)*16 + j  == the 32x32x32_i8 operand
// layout.  One contiguous 1KB transaction per fragment.
// ---------------------------------------------------------------------------
__global__ __launch_bounds__(128) void normq_kernel(
    const float* __restrict__ w1, const float* __restrict__ data,
    signed char* __restrict__ wqf, signed char* __restrict__ dqf,
    float* __restrict__ wsc, float* __restrict__ dsc)
{
  int row = blockIdx.x;
  const bool isW = (row < N_P);
  const float* in;
  signed char* dst; float* sc;
  if (isW) { in = w1;   dst = wqf; sc = wsc; }
  else     { in = data; dst = dqf; sc = dsc; row -= N_P; }
  const int tid = threadIdx.x;
  const float4 v = *(const float4*)(in + (size_t)row * E_DIM + tid * 4);
  float ss = v.x*v.x + v.y*v.y + v.z*v.z + v.w*v.w;
  float am = fmaxf(fmaxf(fabsf(v.x), fabsf(v.y)), fmaxf(fabsf(v.z), fabsf(v.w)));
  #pragma unroll
  for (int s = 1; s < 64; s <<= 1) {
    ss += __shfl_xor(ss, s);
    am = fmaxf(am, __shfl_xor(am, s));
  }
  __shared__ float pss[2], pam[2];
  if ((tid & 63) == 0) { pss[tid >> 6] = ss; pam[tid >> 6] = am; }
  __syncthreads();
  const float inv = 1.0f / fmaxf(sqrtf(pss[0] + pss[1]), 1e-12f);
  const float m   = fmaxf(fmaxf(pam[0], pam[1]) * inv, 1e-20f);
  const float qs  = 127.0f / m * inv;          // v * qs in [-127, 127]
  char4 o;
  o.x = (signed char)__float2int_rn(v.x * qs);
  o.y = (signed char)__float2int_rn(v.y * qs);
  o.z = (signed char)__float2int_rn(v.z * qs);
  o.w = (signed char)__float2int_rn(v.w * qs);
  // k = tid*4: ks = tid>>3, hi = (tid>>2)&1, byte-in-16 = (tid&3)*4
  const int c32 = row >> 5, rr = row & 31;
  const int ks = tid >> 3, hi = (tid >> 2) & 1;
  *(char4*)(dst + (size_t)(c32 * 16 + ks) * 1024 + (hi * 32 + rr) * 16
                + (tid & 3) * 4) = o;
  if (tid == 0) sc[row] = m * (1.0f / 127.0f);
}

// ---------------------------------------------------------------------------
// Per-wave GEMM+max: wave covers rows [rowGroup*64, +64) (2 x 32x32 m-tiles
// = 2 classes) x cols [colOct*512, +512), swept as 8 col-groups of 64 (2
// n-tiles).  A[2][16] register-resident (128 VGPR, loaded once).  Per kstep:
// 2 B loads (1KB coalesced) + 4 MFMA; B dual-set, loaded 2 ksteps ahead.
// Steps 14/15 prefetch the next col-group's ks0/ks1 (over-read at the last
// group lands in wsc -- readable, harmless).
// ---------------------------------------------------------------------------
#define MF32(a,b,c) __builtin_amdgcn_mfma_i32_32x32x32_i8(a, b, c, 0, 0, 0)

// MFMA on set S for kstep KS, then reload set S with kstep NKS at NOFF.
#define STEP(S,KS,NOFF,NKS) do { \
  acc00 = MF32(A[0][KS], b##S##0, acc00); \
  acc01 = MF32(A[0][KS], b##S##1, acc01); \
  acc10 = MF32(A[1][KS], b##S##0, acc10); \
  acc11 = MF32(A[1][KS], b##S##1, acc11); \
  b##S##0 = *(const i32x4*)(gBc + (NOFF) + (NKS)*1024); \
  b##S##1 = *(const i32x4*)(gBc + (NOFF) + 16384 + (NKS)*1024); \
} while(0)

// Dequant + class max for acc tile (MT,NT).  C/D: col = lane&31,
// row = (j&3) + 8*(j>>2) + 4*hi  [HW-verified m74/m101 + r6 this session].
#define EPI(ACC,MT,NT) do { \
  const float* wscp = wscB + (MT) * 32; \
  const float4 wa = *(const float4*)(wscp);       \
  const float4 wb = *(const float4*)(wscp + 8);   \
  const float4 wc2 = *(const float4*)(wscp + 16); \
  const float4 wd = *(const float4*)(wscp + 24);  \
  float pm =          (float)ACC[0]  * wa.x; \
  pm = fmaxf(pm, (float)ACC[1]  * wa.y);  pm = fmaxf(pm, (float)ACC[2]  * wa.z); \
  pm = fmaxf(pm, (float)ACC[3]  * wa.w);  pm = fmaxf(pm, (float)ACC[4]  * wb.x); \
  pm = fmaxf(pm, (float)ACC[5]  * wb.y);  pm = fmaxf(pm, (float)ACC[6]  * wb.z); \
  pm = fmaxf(pm, (float)ACC[7]  * wb.w);  pm = fmaxf(pm, (float)ACC[8]  * wc2.x); \
  pm = fmaxf(pm, (float)ACC[9]  * wc2.y); pm = fmaxf(pm, (float)ACC[10] * wc2.z); \
  pm = fmaxf(pm, (float)ACC[11] * wc2.w); pm = fmaxf(pm, (float)ACC[12] * wd.x); \
  pm = fmaxf(pm, (float)ACC[13] * wd.y);  pm = fmaxf(pm, (float)ACC[14] * wd.z); \
  pm = fmaxf(pm, (float)ACC[15] * wd.w); \
  pm = fmaxf(pm, __shfl_xor(pm, 32)); \
  if (lane < 32) \
    outp[(size_t)(MT) * B_Q + cc * 64 + (NT) * 32] = pm * dscp[cc * 64 + (NT) * 32]; \
} while(0)

__global__ __launch_bounds__(256, 2) void gemm_max_kernel(
    const signed char* __restrict__ wqf,  // [2000][16][1024] fragment-packed
    const signed char* __restrict__ dqf,  // [128][16][1024]  fragment-packed
    const float* __restrict__ wsc,        // [64000] dequant scales
    const float* __restrict__ dsc,        // [4096]  dequant scales
    float* __restrict__ out)              // [2000][4096]
{
  const int tid  = threadIdx.x;
  const int lane = tid & 63;
  const int wid  = tid >> 6;

  // XCD-aware bijective swizzle: 2000 blocks, 250/XCD; 4 waves/block.
  const int bid  = blockIdx.x;
  const int w    = ((bid & 7) * 250 + (bid >> 3)) * 4 + wid;  // 0..7999
  const int rowGroup = w >> 3;            // 0..999  (64 rows = 2 classes)
  const int colOct   = w & 7;             // 0..7    (512 cols)

  const int hi = lane >> 5;

  // A: all 32 fragments register-resident (2 m-tiles x 16 ksteps).
  const signed char* gAp = wqf + (size_t)rowGroup * 32768 + lane * 16;
  i32x4 A[2][16];
  #pragma unroll
  for (int mt = 0; mt < 2; ++mt)
    #pragma unroll
    for (int ks = 0; ks < 16; ++ks)
      A[mt][ks] = *(const i32x4*)(gAp + mt * 16384 + ks * 1024);

  // B base for first col-group (2 tiles of 16KB); advances 32KB per group.
  const signed char* gBc = dqf + (size_t)colOct * 16 * 16384 + lane * 16;

  i32x4 b00, b01, b10, b11;
  i32x16 acc00, acc01, acc10, acc11;

  // Prologue: B ks0 -> set0, ks1 -> set1.
  b00 = *(const i32x4*)(gBc);
  b01 = *(const i32x4*)(gBc + 16384);
  b10 = *(const i32x4*)(gBc + 1024);
  b11 = *(const i32x4*)(gBc + 16384 + 1024);

  float* outp = out + (size_t)(rowGroup * 2) * B_Q + colOct * 512 + (lane & 31);
  const float* wscB = wsc + rowGroup * 64 + hi * 4;
  const float* dscp = dsc + colOct * 512 + (lane & 31);

  #pragma unroll 1
  for (int cc = 0; cc < 8; ++cc) {
    acc00 = (i32x16)0; acc01 = (i32x16)0;
    acc10 = (i32x16)0; acc11 = (i32x16)0;

    STEP(0,0,  0,2);      STEP(1,1,  0,3);
    STEP(0,2,  0,4);      STEP(1,3,  0,5);
    STEP(0,4,  0,6);      STEP(1,5,  0,7);
    STEP(0,6,  0,8);      STEP(1,7,  0,9);
    STEP(0,8,  0,10);     STEP(1,9,  0,11);
    STEP(0,10, 0,12);     STEP(1,11, 0,13);
    STEP(0,12, 0,14);     STEP(1,13, 0,15);
    STEP(0,14, 32768,0);  STEP(1,15, 32768,1);   // prefetch next group

    EPI(acc00, 0, 0);  EPI(acc01, 0, 1);
    EPI(acc10, 1, 0);  EPI(acc11, 1, 1);

    gBc += 32768;
  }
}

// ---------------------------------------------------------------------------
extern "C" void kernel_launch(void* const* d_in, const int* in_sizes, int n_in,
                              void* d_out, int out_size, void* d_ws, size_t ws_size,
                              hipStream_t stream) {
  const float* data = (const float*)d_in[0];   // [4096][512]
  const float* w1   = (const float*)d_in[1];   // [64000][512]
  float* out = (float*)d_out;                  // [2000][4096]

  signed char* wqf = (signed char*)d_ws;                      // 32.77 MB
  signed char* dqf = wqf + (size_t)N_P * E_DIM;               //  2.10 MB
  float* wsc = (float*)(dqf + (size_t)B_Q * E_DIM);           // 256 KB
  float* dsc = wsc + N_P;                                     //  16 KB

  normq_kernel<<<N_P + B_Q, 128, 0, stream>>>(w1, data, wqf, dqf, wsc, dsc);
  gemm_max_kernel<<<2000, 256, 0, stream>>>(wqf, dqf, wsc, dsc, out);
}